// Round 12
// baseline (153.344 us; speedup 1.0000x reference)
//
#include <hip/hip_runtime.h>

typedef __attribute__((ext_vector_type(8))) short bf16x8;
typedef __attribute__((ext_vector_type(4))) float f32x4;
typedef unsigned short ushort_t;

#define N 4096

__device__ __forceinline__ unsigned short f2bf_rne(float f) {
  unsigned int u = __float_as_uint(f);
  u += 0x7fffu + ((u >> 16) & 1u);
  return (unsigned short)(u >> 16);
}

// One block per row (8192 rows: Z then Y). fp32 row norm + bf16 copy.
__global__ __launch_bounds__(256) void prep_kernel(
    const float* __restrict__ Z, const float* __restrict__ Y,
    ushort_t* __restrict__ Zb, ushort_t* __restrict__ Yb,
    float* __restrict__ norms) {
  const int r = blockIdx.x;
  const bool isZ = (r < N);
  const int rr = isZ ? r : r - N;
  const float* __restrict__ src = (isZ ? Z : Y) + (size_t)rr * N;
  ushort_t* __restrict__ dst = (isZ ? Zb : Yb) + (size_t)rr * N;
  const int t = threadIdx.x;

  float s = 0.f;
#pragma unroll
  for (int j = 0; j < 4; ++j) {
    const float4 v = ((const float4*)src)[j * 256 + t];
    s += v.x * v.x + v.y * v.y + v.z * v.z + v.w * v.w;
    short4 o;
    o.x = (short)f2bf_rne(v.x);
    o.y = (short)f2bf_rne(v.y);
    o.z = (short)f2bf_rne(v.z);
    o.w = (short)f2bf_rne(v.w);
    ((short4*)dst)[j * 256 + t] = o;
  }
#pragma unroll
  for (int off = 32; off > 0; off >>= 1) s += __shfl_down(s, off, 64);
  __shared__ float red[4];
  const int lane = t & 63, w = t >> 6;
  if (lane == 0) red[w] = s;
  __syncthreads();
  if (t == 0) norms[r] = sqrtf(red[0] + red[1] + red[2] + red[3]);
}

// ---- 256x256 tile, BK=64, 8 waves, 2-deep dbuf, 8-phase -----------------
// r11 + NEED-ONLY vmcnt gates: stage schedule = consumption order one full
// iter ahead (ph1-4: tile T+2 -> buf0 regions A0,B0,B1,A1; ph5-8: T+3 ->
// buf1). Every gated region is >=6 phases old; uniform vmcnt(10) (= 5
// younger stages x 2 loads) -> gates are no-ops in steady state. Reads
// pipelined one phase ahead w/ counted lgkmcnt (r11). Regions per buf:
// A0@0 A1@16K B0@32K B1@48K; buf1 = +64K. Swizzle slot ^= row&7.
__global__ __launch_bounds__(512, 2) void gemm_kernel(
    const ushort_t* __restrict__ A,   // Zb [N][N]
    const ushort_t* __restrict__ B,   // Yb [N][N]
    const float* __restrict__ norms,  // [2N]: nx then ny
    float* __restrict__ out) {
  __shared__ __align__(16) char smem[131072];

  const int bid = blockIdx.x;                 // 256 blocks; bijective
  const int swz = (bid & 7) * 32 + (bid >> 3);
  const int tile_row = swz >> 4;
  const int tile_col = swz & 15;

  const int tid = threadIdx.x;
  const int l = tid & 63;
  const int w = tid >> 6;
  const int wr = w >> 2;      // 0..1
  const int wc = w & 3;       // 0..3
  const int li = l & 15;
  const int sl = l >> 4;

  // ---- staging pointers: 8 per-thread pre-swizzled sources --------------
  const ushort_t *pA00, *pA01, *pA10, *pA11, *pB00, *pB01, *pB10, *pB11;
  {
    const int ch0 = tid, ch1 = 512 + tid;
    const int r0 = ch0 >> 3, r1 = ch1 >> 3;
    const int c0 = ((ch0 & 7) ^ (r0 & 7)) * 8;
    const int c1 = ((ch1 & 7) ^ (r1 & 7)) * 8;
    pA00 = A + (size_t)(tile_row * 256 + r0) * N + c0;
    pA01 = A + (size_t)(tile_row * 256 + r1) * N + c1;
    pA10 = A + (size_t)(tile_row * 256 + 128 + r0) * N + c0;
    pA11 = A + (size_t)(tile_row * 256 + 128 + r1) * N + c1;
    pB00 = B + (size_t)(tile_col * 256 + r0) * N + c0;
    pB01 = B + (size_t)(tile_col * 256 + r1) * N + c1;
    pB10 = B + (size_t)(tile_col * 256 + 128 + r0) * N + c0;
    pB11 = B + (size_t)(tile_col * 256 + 128 + r1) * N + c1;
  }

#define GLD(SRC, DST)                                              \
  __builtin_amdgcn_global_load_lds(                                \
      (__attribute__((address_space(1))) void*)(SRC),              \
      (__attribute__((address_space(3))) void*)(DST), 16, 0, 0)
#define STG(REGOFF, P0, P1, KOFF) {                                \
    GLD((P0) + (KOFF), smem + (REGOFF) + w * 1024);                \
    GLD((P1) + (KOFF), smem + (REGOFF) + 8192 + w * 1024); }

  // ---- fragment addressing ----------------------------------------------
  const int rbA = (wr * 64 + li) * 128;
  const int rbB = (wc * 32 + li) * 128;
  const int sx0 = ((sl) ^ (li & 7)) * 16;
  const int sx1 = ((4 + sl) ^ (li & 7)) * 16;

  bf16x8 aC[4][2], bQ0[2][2], bQ1[2][2];
  f32x4 acc[8][4];
#pragma unroll
  for (int m = 0; m < 8; ++m)
#pragma unroll
    for (int n = 0; n < 4; ++n) acc[m][n] = (f32x4){0.f, 0.f, 0.f, 0.f};

#define RD_A(BUFB, QH) { _Pragma("unroll")                                    \
    for (int mfl = 0; mfl < 4; ++mfl) {                                       \
      aC[mfl][0] = *(const bf16x8*)(smem + (BUFB) + (QH)*16384 + rbA +        \
                                    mfl*2048 + sx0);                          \
      aC[mfl][1] = *(const bf16x8*)(smem + (BUFB) + (QH)*16384 + rbA +        \
                                    mfl*2048 + sx1); } }
#define RD_B(DST, BUFB, QH) { _Pragma("unroll")                               \
    for (int nfl = 0; nfl < 2; ++nfl) {                                       \
      DST[nfl][0] = *(const bf16x8*)(smem + (BUFB) + 32768 + (QH)*16384 +     \
                                     rbB + nfl*2048 + sx0);                   \
      DST[nfl][1] = *(const bf16x8*)(smem + (BUFB) + 32768 + (QH)*16384 +     \
                                     rbB + nfl*2048 + sx1); } }

#define MFQ(QM, QN, BF) {                                                     \
    __builtin_amdgcn_s_setprio(1);                                            \
    _Pragma("unroll") for (int kh = 0; kh < 2; ++kh)                          \
    _Pragma("unroll") for (int mfl = 0; mfl < 4; ++mfl)                       \
    _Pragma("unroll") for (int nfl = 0; nfl < 2; ++nfl)                       \
      acc[(QM)*4+mfl][(QN)*2+nfl] = __builtin_amdgcn_mfma_f32_16x16x32_bf16(  \
          aC[mfl][kh], BF[nfl][kh], acc[(QM)*4+mfl][(QN)*2+nfl], 0, 0, 0);    \
    __builtin_amdgcn_s_setprio(0); }

#define SB    __builtin_amdgcn_sched_barrier(0);
#define BAR   __builtin_amdgcn_s_barrier();
#define VMW12 asm volatile("s_waitcnt vmcnt(12)" ::: "memory");
#define VMW10 asm volatile("s_waitcnt vmcnt(10)" ::: "memory");
#define VMW8  asm volatile("s_waitcnt vmcnt(8)" ::: "memory");
#define VMW4  asm volatile("s_waitcnt vmcnt(4)" ::: "memory");
#define VMW2  asm volatile("s_waitcnt vmcnt(2)" ::: "memory");
#define VMW0  asm volatile("s_waitcnt vmcnt(0)" ::: "memory");
#define LGW4 { asm volatile("s_waitcnt lgkmcnt(4)" ::: "memory"); SB }
#define LGW0 { asm volatile("s_waitcnt lgkmcnt(0)" ::: "memory"); SB }

  // ---- prologue: stage T0 + T1 in consumption order; prime q0(T0) -------
  STG(0, pA00, pA01, 0);          // A0(T0)
  STG(32768, pB00, pB01, 0);      // B0(T0)
  STG(49152, pB10, pB11, 0);      // B1(T0)
  STG(16384, pA10, pA11, 0);      // A1(T0)
  STG(65536, pA00, pA01, 64);     // A0(T1)
  STG(98304, pB00, pB01, 64);     // B0(T1)
  STG(114688, pB10, pB11, 64);    // B1(T1)
  STG(81920, pA10, pA11, 64);     // A1(T1)
  VMW12; BAR; SB;
  RD_A(0, 0); RD_B(bQ0, 0, 0);    // q0(T0)

  // ---- main loop: iter k computes T=2k (buf0), T+1 (buf1) ---------------
#pragma unroll 1
  for (int k = 0; k < 31; ++k) {
    // ph1: Q00(T); stage A0(T+2)
    VMW10; BAR; SB;
    RD_B(bQ1, 0, 1);
    STG(0, pA00, pA01, 128);
    LGW4;
    MFQ(0, 0, bQ0);
    // ph2: Q01(T); stage B0(T+2)
    VMW10; BAR;
    STG(32768, pB00, pB01, 128);
    LGW0;
    MFQ(0, 1, bQ1);
    SB;
    RD_A(0, 1);
    // ph3: Q11(T); stage B1(T+2)
    BAR;
    STG(49152, pB10, pB11, 128);
    LGW0;
    MFQ(1, 1, bQ1);
    // ph4: Q10(T); stage A1(T+2)
    VMW10; BAR;
    STG(16384, pA10, pA11, 128);
    MFQ(1, 0, bQ0);
    SB;
    RD_A(65536, 0); RD_B(bQ0, 65536, 0);   // q0(T+1)
    // ph5: Q00(T+1); stage A0(T+3)
    VMW10; BAR; SB;
    RD_B(bQ1, 65536, 1);
    STG(65536, pA00, pA01, 192);
    LGW4;
    MFQ(0, 0, bQ0);
    // ph6: Q01(T+1); stage B0(T+3)
    VMW10; BAR;
    STG(98304, pB00, pB01, 192);
    LGW0;
    MFQ(0, 1, bQ1);
    SB;
    RD_A(65536, 1);
    // ph7: Q11(T+1); stage B1(T+3)
    BAR;
    STG(114688, pB10, pB11, 192);
    LGW0;
    MFQ(1, 1, bQ1);
    // ph8: Q10(T+1); stage A1(T+3)
    VMW10; BAR;
    STG(81920, pA10, pA11, 192);
    MFQ(1, 0, bQ0);
    SB;
    RD_A(0, 0); RD_B(bQ0, 0, 0);           // q0(T+2)
    pA00 += 128; pA01 += 128; pA10 += 128; pA11 += 128;
    pB00 += 128; pB01 += 128; pB10 += 128; pB11 += 128;
  }

  // ---- tail: T=62 (buf0), 63 (buf1); no stages; peeled gates ------------
  // t-ph1
  VMW10; BAR; SB;
  RD_B(bQ1, 0, 1);
  LGW4;
  MFQ(0, 0, bQ0);
  // t-ph2
  VMW8; BAR;
  LGW0;
  MFQ(0, 1, bQ1);
  SB;
  RD_A(0, 1);
  // t-ph3
  BAR;
  LGW0;
  MFQ(1, 1, bQ1);
  // t-ph4
  VMW4; BAR;
  MFQ(1, 0, bQ0);
  SB;
  RD_A(65536, 0); RD_B(bQ0, 65536, 0);
  // t-ph5
  VMW2; BAR; SB;
  RD_B(bQ1, 65536, 1);
  LGW4;
  MFQ(0, 0, bQ0);
  // t-ph6
  VMW0; BAR;
  LGW0;
  MFQ(0, 1, bQ1);
  SB;
  RD_A(65536, 1);
  // t-ph7
  LGW0;
  MFQ(1, 1, bQ1);
  // t-ph8
  MFQ(1, 0, bQ0);

  // ---- epilogue: cosine normalize ---------------------------------------
  const float* nx = norms;
  const float* ny = norms + N;
#pragma unroll
  for (int mf = 0; mf < 8; ++mf) {
#pragma unroll
    for (int r = 0; r < 4; ++r) {
      const int row = tile_row * 256 + (mf >> 2) * 128 + wr * 64 +
                      (mf & 3) * 16 + sl * 4 + r;
      const float nxr = nx[row];
#pragma unroll
      for (int nf = 0; nf < 4; ++nf) {
        const int col = tile_col * 256 + (nf >> 1) * 128 + wc * 32 +
                        (nf & 1) * 16 + li;
        const float denom = fmaxf(nxr * ny[col], 1e-8f);
        out[(size_t)row * N + col] = acc[mf][nf][r] / denom;
      }
    }
  }
}

extern "C" void kernel_launch(void* const* d_in, const int* in_sizes, int n_in,
                              void* d_out, int out_size, void* d_ws, size_t ws_size,
                              hipStream_t stream) {
  const float* Z = (const float*)d_in[0];
  const float* Y = (const float*)d_in[1];
  float* out = (float*)d_out;

  ushort_t* Zb = (ushort_t*)d_ws;
  ushort_t* Yb = Zb + (size_t)N * N;
  float* norms = (float*)(Yb + (size_t)N * N);

  prep_kernel<<<2 * N, 256, 0, stream>>>(Z, Y, Zb, Yb, norms);
  gemm_kernel<<<(N / 256) * (N / 256), 512, 0, stream>>>(Zb, Yb, norms, out);
}